// Round 13
// baseline (208.226 us; speedup 1.0000x reference)
//
#include <hip/hip_runtime.h>
#include <hip/hip_bf16.h>

// Sizes
#define HD   256
#define TT   32
#define MV   4096
#define LD_  24
#define LP_  12
#define LM_  20
#define MAXNZ 96

typedef _Float16 h2v __attribute__((ext_vector_type(2)));
typedef _Float16 h8  __attribute__((ext_vector_type(8)));

__device__ __forceinline__ float fdot2(h2v a, h2v b, float c) {
#if __has_builtin(__builtin_amdgcn_fdot2)
  return __builtin_amdgcn_fdot2(a, b, c, false);
#else
  return c + (float)a[0] * (float)b[0] + (float)a[1] * (float)b[1];
#endif
}

#define PIN2(x) { float _t = __builtin_bit_cast(float, x); \
                  asm volatile("" : "+v"(_t));             \
                  x = __builtin_bit_cast(h2v, _t); }

// K01: merged prep. y<2: whh->f16 transposed chunks (b=y). y>=2: embed+GI (b=y-2).
__global__ __launch_bounds__(768) void k01_prep(
    const float* __restrict__ whh_d, const float* __restrict__ whh_p,
    h8* __restrict__ wt,
    const int* __restrict__ dc, const int* __restrict__ pc,
    const float* __restrict__ demb, const float* __restrict__ pemb,
    const float* __restrict__ wih_d, const float* __restrict__ bih_d,
    const float* __restrict__ wih_p, const float* __restrict__ bih_p,
    float* __restrict__ GI)
{
  if (blockIdx.y < 2) {
    const int i = blockIdx.x, b = blockIdx.y, g = threadIdx.x;
    const float* whh = b ? whh_p : whh_d;
    const float* src = whh + (size_t)g * HD + 8 * i;
    h8 v;
#pragma unroll
    for (int e = 0; e < 8; ++e) v[e] = (_Float16)src[e];
    wt[((size_t)b * 32 + i) * 768 + g] = v;
    return;
  }
  const int t = blockIdx.x, b = blockIdx.y - 2;
  const int* codes = b ? pc : dc;
  const int L = b ? LP_ : LD_;
  const float* emb = b ? pemb : demb;
  const float* wih = b ? wih_p : wih_d;
  const float* bih = b ? bih_p : bih_d;
  __shared__ float s[HD];
  const int j = threadIdx.x;
  if (j < HD) {
    float acc = 0.f;
    for (int l = 0; l < L; ++l) acc += emb[(size_t)codes[t * L + l] * HD + j];
    s[j] = acc;
  }
  __syncthreads();
  const int g = j;
  float acc = bih[g];
  const float* wr = wih + (size_t)g * HD;
  for (int k = 0; k < HD; k += 4) {
    float4 w4 = *(const float4*)(wr + k);
    acc = fmaf(w4.x, s[k], acc);
    acc = fmaf(w4.y, s[k + 1], acc);
    acc = fmaf(w4.z, s[k + 2], acc);
    acc = fmaf(w4.w, s[k + 3], acc);
  }
  GI[((size_t)b * TT + t) * 768 + g] = acc;
}

// K2: sequential GRU, pair-split (EXACT round-9 version that held its regs).
// 512 threads = 2 waves/SIMD under waves_per_eu(2,2) => 256-reg budget.
// Thread (p=t>>1, hk=t&1): 3 gate rows x 128 K-elems = 192 packed-f16 regs.
__global__ __launch_bounds__(512)
__attribute__((amdgpu_waves_per_eu(2, 2)))
void k2_gru(
    const float* __restrict__ GI, const h8* __restrict__ wt,
    const float* __restrict__ bhh_d, const float* __restrict__ bhh_p,
    float* __restrict__ feats)
{
  const int b = blockIdx.x, t = threadIdx.x;
  const int p = t >> 1;        // h-dim 0..255
  const int hk = t & 1;        // K-half
  const float* gi = GI + (size_t)b * TT * 768;
  const float* bhh = b ? bhh_p : bhh_d;

  __shared__ h8 hbuf[2][32];   // h as packed f16, double-buffered

  h2v w[192];
  {
    const h8* wbase = wt + (size_t)b * 32 * 768;
#pragma unroll
    for (int r3 = 0; r3 < 3; ++r3) {
#pragma unroll
      for (int ii = 0; ii < 16; ++ii) {
        union { h8 v; h2v q[4]; } u;
        u.v = wbase[(size_t)(hk * 16 + ii) * 768 + r3 * 256 + p];
        w[(r3 * 16 + ii) * 4 + 0] = u.q[0];
        w[(r3 * 16 + ii) * 4 + 1] = u.q[1];
        w[(r3 * 16 + ii) * 4 + 2] = u.q[2];
        w[(r3 * 16 + ii) * 4 + 3] = u.q[3];
      }
    }
  }
#pragma unroll
  for (int i = 0; i < 192; ++i) PIN2(w[i])

  const float bh_r = bhh[p], bh_z = bhh[256 + p], bh_n = bhh[512 + p];
  float hreg = 0.f;
  if (t < 256) ((_Float16*)&hbuf[0][0])[t] = (_Float16)0.f;
  __syncthreads();

  for (int tt = 0; tt < TT; ++tt) {
    const float* git = gi + tt * 768;
    float ir = 0.f, iz = 0.f, inn = 0.f;
    if (hk == 0) { ir = git[p]; iz = git[256 + p]; inn = git[512 + p]; }

    const h8* hb = hbuf[tt & 1];
    float dr0 = 0.f, dr1 = 0.f, dz0 = 0.f, dz1 = 0.f, dn0 = 0.f, dn1 = 0.f;
#pragma unroll
    for (int ii = 0; ii < 16; ++ii) {
      union { h8 v; h2v q[4]; } u;
      u.v = hb[hk * 16 + ii];
      dr0 = fdot2(w[(0 * 16 + ii) * 4 + 0], u.q[0], dr0);
      dr1 = fdot2(w[(0 * 16 + ii) * 4 + 1], u.q[1], dr1);
      dr0 = fdot2(w[(0 * 16 + ii) * 4 + 2], u.q[2], dr0);
      dr1 = fdot2(w[(0 * 16 + ii) * 4 + 3], u.q[3], dr1);
      dz0 = fdot2(w[(1 * 16 + ii) * 4 + 0], u.q[0], dz0);
      dz1 = fdot2(w[(1 * 16 + ii) * 4 + 1], u.q[1], dz1);
      dz0 = fdot2(w[(1 * 16 + ii) * 4 + 2], u.q[2], dz0);
      dz1 = fdot2(w[(1 * 16 + ii) * 4 + 3], u.q[3], dz1);
      dn0 = fdot2(w[(2 * 16 + ii) * 4 + 0], u.q[0], dn0);
      dn1 = fdot2(w[(2 * 16 + ii) * 4 + 1], u.q[1], dn1);
      dn0 = fdot2(w[(2 * 16 + ii) * 4 + 2], u.q[2], dn0);
      dn1 = fdot2(w[(2 * 16 + ii) * 4 + 3], u.q[3], dn1);
    }
    float dr = dr0 + dr1, dz = dz0 + dz1, dn = dn0 + dn1;
    dr += __shfl_xor(dr, 1, 64);
    dz += __shfl_xor(dz, 1, 64);
    dn += __shfl_xor(dn, 1, 64);
    if (hk == 0) {
      const float hr = dr + bh_r, hz = dz + bh_z, hn = dn + bh_n;
      const float r = 1.f / (1.f + __expf(-(ir + hr)));
      const float z = 1.f / (1.f + __expf(-(iz + hz)));
      const float n = tanhf(inn + r * hn);
      hreg = (1.f - z) * n + z * hreg;
      ((_Float16*)&hbuf[(tt & 1) ^ 1][0])[p] = (_Float16)hreg;
      feats[(size_t)tt * 512 + b * HD + p] = hreg;
    }
    __syncthreads();
  }
}

// Chunked scan: one row per wave, row streamed in 4 chunks of 4xfloat4
// (16 regs/chunk, A/B ping-pong = 32 data regs + temps ~= 52 <= 64-reg
// budget -> spill-proof at max occupancy). Prefix base carries across
// chunks; 8 blocks/CU give 32 waves/CU of TLP to hide the emit phases.
#define LOADC(V0, V1, V2, V3, COFF)                               \
  V0 = *(const float4*)(adj + (COFF) + 0 * 256 + lane * 4);       \
  V1 = *(const float4*)(adj + (COFF) + 1 * 256 + lane * 4);       \
  V2 = *(const float4*)(adj + (COFF) + 2 * 256 + lane * 4);       \
  V3 = *(const float4*)(adj + (COFF) + 3 * 256 + lane * 4);

#define PROCC(V0, V1, V2, V3, COFF)                                     \
  {                                                                     \
    int cl = 0;                                                         \
    cl += (V0.x != 0.f) + (V0.y != 0.f) + (V0.z != 0.f) + (V0.w != 0.f);\
    cl += (V1.x != 0.f) + (V1.y != 0.f) + (V1.z != 0.f) + (V1.w != 0.f);\
    cl += (V2.x != 0.f) + (V2.y != 0.f) + (V2.z != 0.f) + (V2.w != 0.f);\
    cl += (V3.x != 0.f) + (V3.y != 0.f) + (V3.z != 0.f) + (V3.w != 0.f);\
    int pref = cl;                                                      \
    _Pragma("unroll")                                                   \
    for (int ofs = 1; ofs < 64; ofs <<= 1) {                            \
      int v = __shfl_up(pref, ofs, 64);                                 \
      if (lane >= ofs) pref += v;                                       \
    }                                                                   \
    const int ctotal = __shfl(pref, 63, 64);                            \
    int pos = base + pref - cl;                                         \
    const float4 vv4[4] = {V0, V1, V2, V3};                             \
    _Pragma("unroll")                                                   \
    for (int k = 0; k < 4; ++k) {                                       \
      const float vv[4] = {vv4[k].x, vv4[k].y, vv4[k].z, vv4[k].w};     \
      _Pragma("unroll")                                                 \
      for (int e = 0; e < 4; ++e) {                                     \
        if (vv[e] != 0.f) {                                             \
          if (pos < MAXNZ) { cg[pos] = (COFF) + k * 256 + lane * 4 + e; \
                             vg[pos] = vv[e]; }                         \
          ++pos;                                                        \
        }                                                               \
      }                                                                 \
    }                                                                   \
    base += ctotal;                                                     \
  }

__global__ __launch_bounds__(256) void k3_scan(
    const float* __restrict__ adj_e, const float* __restrict__ adj_d,
    int* __restrict__ cnt_g, int* __restrict__ cols_g,
    float* __restrict__ vals_g)
{
  const int w = threadIdx.x >> 6, lane = threadIdx.x & 63;
  const int rg = blockIdx.x * 4 + w;          // [0, 8192)
  const int bsel = rg >> 12;
  const int r = rg & (MV - 1);
  const float* adj = (bsel ? adj_d : adj_e) + (size_t)r * MV;
  int* cg = cols_g + (size_t)rg * MAXNZ;
  float* vg = vals_g + (size_t)rg * MAXNZ;

  int base = 0;
  float4 a0, a1, a2, a3, b0, b1, b2, b3;
  LOADC(a0, a1, a2, a3, 0)
  LOADC(b0, b1, b2, b3, 1024)
  PROCC(a0, a1, a2, a3, 0)
  LOADC(a0, a1, a2, a3, 2048)
  PROCC(b0, b1, b2, b3, 1024)
  LOADC(b0, b1, b2, b3, 3072)
  PROCC(a0, a1, a2, a3, 2048)
  PROCC(b0, b1, b2, b3, 3072)

  if (lane == 0) cnt_g[rg] = base > MAXNZ ? MAXNZ : base;
}

// K2b: queries[t,j] = q_b[j] + sum_k relu(feats[t,k]) * q_w[k,j]
__global__ __launch_bounds__(256) void k2b_queries(
    const float* __restrict__ feats, const float* __restrict__ q_w,
    const float* __restrict__ q_b, float* __restrict__ queries)
{
  const int t = blockIdx.x, j = threadIdx.x;
  __shared__ float f[512];
  f[j] = fmaxf(feats[(size_t)t * 512 + j], 0.f);
  f[j + 256] = fmaxf(feats[(size_t)t * 512 + 256 + j], 0.f);
  __syncthreads();
  float acc = q_b[j];
  for (int k = 0; k < 512; ++k) acc = fmaf(f[k], q_w[(size_t)k * HD + j], acc);
  queries[(size_t)t * HD + j] = acc;
}

// K45: fused h1-build + z GEMM. 512 threads.
__global__ __launch_bounds__(512) void k45_z(
    const int* __restrict__ cnt_g, const int* __restrict__ cols_g,
    const float* __restrict__ vals_g,
    const float* __restrict__ w1_e, const float* __restrict__ b1_e,
    const float* __restrict__ w1_d, const float* __restrict__ b1_d,
    const float* __restrict__ w2_e, const float* __restrict__ w2_d,
    float* __restrict__ zz)
{
  const int blk = blockIdx.x, b = blockIdx.y;
  const int t = threadIdx.x;
  __shared__ float tile[8][HD];
  __shared__ float part[8][HD];

  // phase 1: gather (one wave per row)
  {
    const int w = t >> 6, lane = t & 63;
    const int rg = b * MV + blk * 8 + w;
    const float* w1 = b ? w1_d : w1_e;
    const float* b1 = b ? b1_d : b1_e;
    const int n = cnt_g[rg];
    const int* cg = cols_g + (size_t)rg * MAXNZ;
    const float* vg = vals_g + (size_t)rg * MAXNZ;
    float4 acc = *(const float4*)(b1 + lane * 4);
    for (int k = 0; k < n; ++k) {
      const int col = cg[k];
      const float v = vg[k];
      const float4 wv4 = *(const float4*)(w1 + (size_t)col * HD + lane * 4);
      acc.x = fmaf(v, wv4.x, acc.x);
      acc.y = fmaf(v, wv4.y, acc.y);
      acc.z = fmaf(v, wv4.z, acc.z);
      acc.w = fmaf(v, wv4.w, acc.w);
    }
    float4* dst = (float4*)&tile[w][lane * 4];
    dst->x = fmaxf(acc.x, 0.f); dst->y = fmaxf(acc.y, 0.f);
    dst->z = fmaxf(acc.z, 0.f); dst->w = fmaxf(acc.w, 0.f);
  }
  __syncthreads();

  // phase 2: GEMM
  const int j = t & 255, half = t >> 8;
  const float* w2 = b ? w2_d : w2_e;
  float acc[8];
#pragma unroll
  for (int r = 0; r < 8; ++r) acc[r] = 0.f;
  const int k0 = half * 128;
  for (int k = k0; k < k0 + 128; k += 4) {
    float wa = w2[(size_t)(k + 0) * HD + j];
    float wb = w2[(size_t)(k + 1) * HD + j];
    float wc = w2[(size_t)(k + 2) * HD + j];
    float wd = w2[(size_t)(k + 3) * HD + j];
#pragma unroll
    for (int r = 0; r < 8; ++r) {
      float4 tv = *(const float4*)&tile[r][k];
      acc[r] = fmaf(tv.x, wa, acc[r]);
      acc[r] = fmaf(tv.y, wb, acc[r]);
      acc[r] = fmaf(tv.z, wc, acc[r]);
      acc[r] = fmaf(tv.w, wd, acc[r]);
    }
  }
  if (half == 1) {
#pragma unroll
    for (int r = 0; r < 8; ++r) part[r][j] = acc[r];
  }
  __syncthreads();
  if (half == 0) {
    float* zb = zz + (size_t)b * MV * HD + (size_t)blk * 8 * HD;
#pragma unroll
    for (int r = 0; r < 8; ++r) zb[r * HD + j] = acc[r] + part[r][j];
  }
}

// K5: prior + s1
__global__ __launch_bounds__(256) void k5_prior(
    const float* __restrict__ zz, const int* __restrict__ cnt_g,
    const int* __restrict__ cols_g, const float* __restrict__ vals_g,
    const float* __restrict__ b2_e, const float* __restrict__ b2_d,
    const float* __restrict__ inter, const float* __restrict__ queries,
    float* __restrict__ prior, float* __restrict__ s1)
{
  const int r = blockIdx.x, j = threadIdx.x;
  __shared__ float red[256];
  float acc_e = b2_e[j];
  {
    const int ne = cnt_g[r];
    const int* ce = cols_g + (size_t)r * MAXNZ;
    const float* ve = vals_g + (size_t)r * MAXNZ;
    for (int k = 0; k < ne; ++k)
      acc_e = fmaf(ve[k], zz[(size_t)ce[k] * HD + j], acc_e);
  }
  float acc_d = b2_d[j];
  {
    const int nd = cnt_g[MV + r];
    const int* cd = cols_g + (size_t)(MV + r) * MAXNZ;
    const float* vd = vals_g + (size_t)(MV + r) * MAXNZ;
    const float* zd = zz + (size_t)MV * HD;
    for (int k = 0; k < nd; ++k)
      acc_d = fmaf(vd[k], zd[(size_t)cd[k] * HD + j], acc_d);
  }
  const float pr = acc_e - inter[0] * acc_d;
  prior[(size_t)r * HD + j] = pr;
  red[j] = queries[31 * HD + j] * pr;
  __syncthreads();
  for (int s = 128; s > 0; s >>= 1) {
    if (j < s) red[j] += red[j + s];
    __syncthreads();
  }
  if (j == 0) s1[r] = red[0];
}

// K6a: softmaxes
__global__ __launch_bounds__(1024) void k6a_softmax(
    const float* __restrict__ s1, const float* __restrict__ queries,
    float* __restrict__ w_emb, float* __restrict__ visw)
{
  const int j = threadIdx.x;
  __shared__ float red[1024];
  __shared__ float s2[31];
  float m = -1e30f;
  for (int i = j; i < MV; i += 1024) m = fmaxf(m, s1[i]);
  red[j] = m;
  __syncthreads();
  for (int s = 512; s > 0; s >>= 1) {
    if (j < s) red[j] = fmaxf(red[j], red[j + s]);
    __syncthreads();
  }
  const float mx = red[0];
  __syncthreads();
  float sum = 0.f;
  for (int i = j; i < MV; i += 1024) sum += __expf(s1[i] - mx);
  red[j] = sum;
  __syncthreads();
  for (int s = 512; s > 0; s >>= 1) {
    if (j < s) red[j] += red[j + s];
    __syncthreads();
  }
  const float inv = 1.f / red[0];
  for (int i = j; i < MV; i += 1024) w_emb[i] = __expf(s1[i] - mx) * inv;

  if (j < 31) {
    float acc = 0.f;
    for (int k = 0; k < HD; ++k)
      acc = fmaf(queries[31 * HD + k], queries[(size_t)j * HD + k], acc);
    s2[j] = acc;
  }
  __syncthreads();
  if (j == 0) {
    float mm = -1e30f;
    for (int t = 0; t < 31; ++t) mm = fmaxf(mm, s2[t]);
    float ss = 0.f;
    for (int t = 0; t < 31; ++t) ss += __expf(s2[t] - mm);
    const float is = 1.f / ss;
    for (int t = 0; t < 31; ++t) visw[t] = __expf(s2[t] - mm) * is;
  }
}

// K7: output projection with wv computed in-block (k6b folded in).
__global__ __launch_bounds__(512) void k7_out(
    const float* __restrict__ prior, const float* __restrict__ w_emb,
    const float* __restrict__ visw, const int* __restrict__ med,
    const float* __restrict__ proj_w, const float* __restrict__ proj_b,
    float* __restrict__ out)
{
  const int blk = blockIdx.x;
  const int t = threadIdx.x;
  const int j = t & 255, half = t >> 8;
  const int r0 = blk * 8;
  __shared__ float tile[8][HD];
  __shared__ float part[8][HD];
  __shared__ float we[8], wvv[8];
  __shared__ int mc[31 * LM_];
  {
    float4* t4 = (float4*)tile;
    const float4* s4 = (const float4*)(prior + (size_t)r0 * HD);
    t4[t] = s4[t];
  }
  for (int i = t; i < 31 * LM_; i += 512) mc[i] = med[i];
  if (t < 8) we[t] = w_emb[r0 + t];
  __syncthreads();

  if (half == 0) {
    const int r = j >> 5, tp = j & 31;
    float contrib = 0.f;
    if (tp < 31) {
      const int m = r0 + r;
      bool found = false;
#pragma unroll
      for (int l = 0; l < LM_; ++l) found = found || (mc[tp * LM_ + l] == m);
      if (found) contrib = visw[tp];
    }
#pragma unroll
    for (int msk = 16; msk > 0; msk >>= 1) contrib += __shfl_xor(contrib, msk, 32);
    if (tp == 0) wvv[r] = contrib;
  }

  const float* wmat = proj_w + (size_t)half * HD * HD;
  float acc[8];
#pragma unroll
  for (int r = 0; r < 8; ++r) acc[r] = 0.f;
  for (int k = 0; k < HD; k += 4) {
    float wa = wmat[(size_t)(k + 0) * HD + j];
    float wb = wmat[(size_t)(k + 1) * HD + j];
    float wc = wmat[(size_t)(k + 2) * HD + j];
    float wd = wmat[(size_t)(k + 3) * HD + j];
#pragma unroll
    for (int r = 0; r < 8; ++r) {
      float4 tv = *(const float4*)&tile[r][k];
      acc[r] = fmaf(tv.x, wa, acc[r]);
      acc[r] = fmaf(tv.y, wb, acc[r]);
      acc[r] = fmaf(tv.z, wc, acc[r]);
      acc[r] = fmaf(tv.w, wd, acc[r]);
    }
  }
  if (half == 1) {
#pragma unroll
    for (int r = 0; r < 8; ++r) part[r][j] = acc[r];
  }
  __syncthreads();
  if (half == 0) {
    const float pb = proj_b[j];
#pragma unroll
    for (int r = 0; r < 8; ++r)
      out[(size_t)(r0 + r) * HD + j] = we[r] * acc[r] + wvv[r] * part[r][j] + pb;
  }
}

extern "C" void kernel_launch(void* const* d_in, const int* in_sizes, int n_in,
                              void* d_out, int out_size, void* d_ws, size_t ws_size,
                              hipStream_t stream) {
  const int* diag_codes = (const int*)d_in[0];
  const int* proc_codes = (const int*)d_in[1];
  const int* med_codes  = (const int*)d_in[2];
  const float* diag_emb = (const float*)d_in[3];
  const float* proc_emb = (const float*)d_in[4];
  const float* wih_d = (const float*)d_in[5];
  const float* whh_d = (const float*)d_in[6];
  const float* bih_d = (const float*)d_in[7];
  const float* bhh_d = (const float*)d_in[8];
  const float* wih_p = (const float*)d_in[9];
  const float* whh_p = (const float*)d_in[10];
  const float* bih_p = (const float*)d_in[11];
  const float* bhh_p = (const float*)d_in[12];
  const float* q_w = (const float*)d_in[13];
  const float* q_b = (const float*)d_in[14];
  const float* adj_ehr = (const float*)d_in[15];
  const float* adj_ddi = (const float*)d_in[16];
  const float* w1_ehr = (const float*)d_in[17];
  const float* b1_ehr = (const float*)d_in[18];
  const float* w2_ehr = (const float*)d_in[19];
  const float* b2_ehr = (const float*)d_in[20];
  const float* w1_ddi = (const float*)d_in[21];
  const float* b1_ddi = (const float*)d_in[22];
  const float* w2_ddi = (const float*)d_in[23];
  const float* b2_ddi = (const float*)d_in[24];
  const float* inter = (const float*)d_in[25];
  const float* proj_w = (const float*)d_in[26];
  const float* proj_b = (const float*)d_in[27];
  float* out = (float*)d_out;

  float* ws = (float*)d_ws;
  size_t off = 0;
  float* GI      = ws + off; off += 2 * TT * 768;        // 49152
  float* feats   = ws + off; off += TT * 512;            // 16384
  float* queries = ws + off; off += TT * HD;             // 8192
  float* zz      = ws + off; off += 2 * (size_t)MV * HD; // 2M
  float* prior   = ws + off; off += (size_t)MV * HD;     // 1M
  float* s1      = ws + off; off += MV;
  float* w_emb   = ws + off; off += MV;
  float* visw    = ws + off; off += 32;
  int*   cnt_g   = (int*)(ws + off); off += 2 * MV;
  int*   cols_g  = (int*)(ws + off); off += 2 * (size_t)MV * MAXNZ;
  float* vals_g  = ws + off; off += 2 * (size_t)MV * MAXNZ;
  h8*    wt      = (h8*)(ws + off); off += 2 * 32 * 768 * 4; // 786432 B
  (void)ws_size; (void)in_sizes; (void)n_in; (void)out_size;

  k01_prep<<<dim3(32, 4), 768, 0, stream>>>(whh_d, whh_p, wt,
      diag_codes, proc_codes, diag_emb, proc_emb,
      wih_d, bih_d, wih_p, bih_p, GI);
  k3_scan<<<2 * MV / 4, 256, 0, stream>>>(adj_ehr, adj_ddi,
      cnt_g, cols_g, vals_g);
  k2_gru<<<2, 512, 0, stream>>>(GI, wt, bhh_d, bhh_p, feats);
  k2b_queries<<<TT, 256, 0, stream>>>(feats, q_w, q_b, queries);
  k45_z<<<dim3(MV / 8, 2), 512, 0, stream>>>(cnt_g, cols_g, vals_g,
      w1_ehr, b1_ehr, w1_ddi, b1_ddi, w2_ehr, w2_ddi, zz);
  k5_prior<<<MV, 256, 0, stream>>>(zz, cnt_g, cols_g, vals_g, b2_ehr, b2_ddi,
      inter, queries, prior, s1);
  k6a_softmax<<<1, 1024, 0, stream>>>(s1, queries, w_emb, visw);
  k7_out<<<MV / 8, 512, 0, stream>>>(prior, w_emb, visw, med_codes,
      proj_w, proj_b, out);
}